// Round 9
// baseline (149.608 us; speedup 1.0000x reference)
//
#include <hip/hip_runtime.h>

// DistributionLoss: local 7x7xC std (zero-padded) of two [16,3,512,512] fp32
// tensors, smooth-L1 mean between std maps -> scalar.
//
// R9: cross-job double-buffered ping-pong.
//  - Each block owns a 64x16 output tile position and 8 jobs:
//    (4 batches) x (pred, tgt). LDS holds TWO h/g buffers (24 KB total).
//  - Per job: hstore into buf[j&1]; ONE barrier; issue job j+1's 9-18
//    float4 loads; phase B (vertical 7-tap + std + park/fuse) runs while
//    those loads are in flight. Loads are never separated from compute by
//    a barrier -> one exposed HBM latency per 8 jobs instead of per phase.
//  - Buffer parity alternates per job; the per-job barrier fences WAR on
//    the opposite buffer (phaseB(j-1) finished before any thread reaches
//    hstore(j+1)).
//  - 1024 blocks (4/CU), 6 possible by LDS; VGPR ~110 under bounds(256,2).

#define K     7
#define PAD   3
#define TSX   64
#define TSY   16
#define HR    (TSY + K - 1)   // 22 halo rows
#define LDSW  68              // LDS row stride (floats)
#define NT    256
#define NTASK (HR * 16)       // 352 phase-A tasks

struct T9    { float4 A0, B0, C0, A1, B1, C1, A2, B2, C2; };
struct TaskD { int row, cg, gyc, gx0; float m; bool lOK, rOK; };

__device__ __forceinline__ float4 ld4(const float* p) { return *(const float4*)p; }

__device__ __forceinline__ float4 add3(float4 a, float4 b, float4 c) {
    return make_float4(a.x + b.x + c.x, a.y + b.y + c.y,
                       a.z + b.z + c.z, a.w + b.w + c.w);
}
__device__ __forceinline__ float4 sq3(float4 a, float4 b, float4 c) {
    return make_float4(fmaf(a.x, a.x, fmaf(b.x, b.x, c.x * c.x)),
                       fmaf(a.y, a.y, fmaf(b.y, b.y, c.y * c.y)),
                       fmaf(a.z, a.z, fmaf(b.z, b.z, c.z * c.z)),
                       fmaf(a.w, a.w, fmaf(b.w, b.w, c.w * c.w)));
}

__device__ __forceinline__ TaskD decode(int task, int tx0, int ty0) {
    TaskD d;
    d.row = task >> 4;
    d.cg  = task & 15;
    int gy = ty0 - PAD + d.row;
    d.m   = ((unsigned)gy < 512u) ? 1.0f : 0.0f;
    d.gyc = min(max(gy, 0), 511);
    d.gx0 = tx0 + (d.cg << 2);
    d.lOK = (d.gx0 > 0);
    d.rOK = (d.gx0 < 508);
    return d;
}

__device__ __forceinline__ T9 load9(const float* base, size_t plane, TaskD d) {
    const float4 z4 = make_float4(0.f, 0.f, 0.f, 0.f);
    const float* r0 = base + (size_t)d.gyc * 512 + d.gx0;
    const float* r1 = r0 + plane;
    const float* r2 = r1 + plane;
    T9 t;
    t.A0 = d.lOK ? ld4(r0 - 4) : z4;  t.B0 = ld4(r0);  t.C0 = d.rOK ? ld4(r0 + 4) : z4;
    t.A1 = d.lOK ? ld4(r1 - 4) : z4;  t.B1 = ld4(r1);  t.C1 = d.rOK ? ld4(r1 + 4) : z4;
    t.A2 = d.lOK ? ld4(r2 - 4) : z4;  t.B2 = ld4(r2);  t.C2 = d.rOK ? ld4(r2 + 4) : z4;
    return t;
}

__device__ __forceinline__ void hstore(T9 t, TaskD d,
                                       float (*sh_s)[LDSW], float (*sh_q)[LDSW]) {
    float4 tl = add3(t.A0, t.A1, t.A2);
    float4 tm = add3(t.B0, t.B1, t.B2);
    float4 tr = add3(t.C0, t.C1, t.C2);
    float4 ul = sq3(t.A0, t.A1, t.A2);
    float4 um = sq3(t.B0, t.B1, t.B2);
    float4 ur = sq3(t.C0, t.C1, t.C2);

    float h0 = tl.y + tl.z + tl.w + tm.x + tm.y + tm.z + tm.w;
    float h1 = h0 - tl.y + tr.x;
    float h2 = h1 - tl.z + tr.y;
    float h3 = h2 - tl.w + tr.z;
    float g0 = ul.y + ul.z + ul.w + um.x + um.y + um.z + um.w;
    float g1 = g0 - ul.y + ur.x;
    float g2 = g1 - ul.z + ur.y;
    float g3 = g2 - ul.w + ur.z;

    *(float4*)&sh_s[d.row][d.cg << 2] =
        make_float4(h0 * d.m, h1 * d.m, h2 * d.m, h3 * d.m);
    *(float4*)&sh_q[d.row][d.cg << 2] =
        make_float4(g0 * d.m, g1 * d.m, g2 * d.m, g3 * d.m);
}

__global__ __launch_bounds__(NT, 2) void dist_loss_kernel(
    const float* __restrict__ pred,
    const float* __restrict__ tgt,
    float* __restrict__ out)
{
    constexpr int   C = 3, H = 512, W = 512;
    constexpr float INV_N     = 1.0f / (C * K * K);              // 1/147
    constexpr float INV_TOTAL = 1.0f / (16.0f * 512.0f * 512.0f);

    __shared__ float sh_s[2][HR][LDSW];
    __shared__ float sh_q[2][HR][LDSW];

    const int    tid  = threadIdx.x;
    const int    tx0  = blockIdx.x * TSX;
    const int    ty0  = blockIdx.y * TSY;
    const int    z0   = blockIdx.z * 4;          // 4 batches per block
    const size_t plane = (size_t)H * W;
    const size_t CP    = (size_t)C * plane;
    const float4 z4 = make_float4(0.f, 0.f, 0.f, 0.f);

    const bool  has1 = (tid < NTASK - NT);       // 96 threads own a 2nd task
    const TaskD d0 = decode(tid, tx0, ty0);
    const TaskD d1 = decode(has1 ? tid + NT : tid, tx0, ty0);

    const float* pb = pred + (size_t)z0 * CP;
    const float* tb = tgt  + (size_t)z0 * CP;

    float4 pSTD;                 // parked std quad (pred) for current batch
    float  acc = 0.0f;

    // prime job 0 (pred, batch z0)
    T9 x0 = load9(pb, plane, d0);
    T9 x1 = load9(pb, plane, d1);

    for (int j = 0; j < 8; ++j) {
        const int bufi = j & 1;

        hstore(x0, d0, sh_s[bufi], sh_q[bufi]);
        if (has1) hstore(x1, d1, sh_s[bufi], sh_q[bufi]);
        __syncthreads();

        // issue next job's loads NOW; they fly during phase B below
        if (j < 7) {
            const int nj = j + 1;
            const float* nb = ((nj & 1) ? tb : pb) + (size_t)(nj >> 1) * CP;
            x0 = load9(nb, plane, d0);
            x1 = load9(nb, plane, d1);
        }

        // ---- Phase B: vertical 7-tap + std; exactly 1 row-quad per thread
        {
            const int r  = tid >> 4;           // output row 0..15
            const int xo = (tid & 15) << 2;    // col offset

            float4 S = z4, Q = z4;
            #pragma unroll
            for (int k = 0; k < K; ++k) {
                float4 hv = *(const float4*)&sh_s[bufi][r + k][xo];
                float4 gv = *(const float4*)&sh_q[bufi][r + k][xo];
                S.x += hv.x; S.y += hv.y; S.z += hv.z; S.w += hv.w;
                Q.x += gv.x; Q.y += gv.y; Q.z += gv.z; Q.w += gv.w;
            }

            float4 sd;
            {
                float mux = S.x * INV_N, muy = S.y * INV_N,
                      muz = S.z * INV_N, muw = S.w * INV_N;
                sd.x = sqrtf(fmaf(-mux, mux, Q.x * INV_N) + 1e-8f);
                sd.y = sqrtf(fmaf(-muy, muy, Q.y * INV_N) + 1e-8f);
                sd.z = sqrtf(fmaf(-muz, muz, Q.z * INV_N) + 1e-8f);
                sd.w = sqrtf(fmaf(-muw, muw, Q.w * INV_N) + 1e-8f);
            }

            if ((j & 1) == 0) {
                pSTD = sd;                     // pred: park
            } else {                           // tgt: fuse smooth-L1
                float d, ad;
                d = pSTD.x - sd.x; ad = fabsf(d);
                acc += (ad < 1.0f) ? 0.5f * d * d : (ad - 0.5f);
                d = pSTD.y - sd.y; ad = fabsf(d);
                acc += (ad < 1.0f) ? 0.5f * d * d : (ad - 0.5f);
                d = pSTD.z - sd.z; ad = fabsf(d);
                acc += (ad < 1.0f) ? 0.5f * d * d : (ad - 0.5f);
                d = pSTD.w - sd.w; ad = fabsf(d);
                acc += (ad < 1.0f) ? 0.5f * d * d : (ad - 0.5f);
            }
        }
        // no trailing barrier: next hstore writes the OTHER buffer, and the
        // per-job barrier above fences the WAR two jobs apart.
    }

    // ---- block reduction: wave64 shuffle, cross-wave via LDS, one atomic
    #pragma unroll
    for (int off = 32; off > 0; off >>= 1)
        acc += __shfl_down(acc, off, 64);

    __shared__ float wave_sums[NT / 64];
    if ((tid & 63) == 0) wave_sums[tid >> 6] = acc;
    __syncthreads();
    if (tid == 0) {
        float s = 0.0f;
        #pragma unroll
        for (int w = 0; w < NT / 64; ++w) s += wave_sums[w];
        atomicAdd(out, s * INV_TOTAL);
    }
}

extern "C" void kernel_launch(void* const* d_in, const int* in_sizes, int n_in,
                              void* d_out, int out_size, void* d_ws, size_t ws_size,
                              hipStream_t stream) {
    const float* pred = (const float*)d_in[0];
    const float* tgt  = (const float*)d_in[1];
    float* out = (float*)d_out;

    hipMemsetAsync(out, 0, sizeof(float), stream);

    // 8 x 32 tile positions x 4 batch groups = 1024 blocks (4/CU)
    dim3 grid(512 / TSX, 512 / TSY, 4);
    dist_loss_kernel<<<grid, NT, 0, stream>>>(pred, tgt, out);
}